// Round 1
// baseline (170.191 us; speedup 1.0000x reference)
//
#include <hip/hip_runtime.h>

#define K 32
#define R 8
#define DESC 603

__global__ __launch_bounds__(256)
void desc_kernel(const float* __restrict__ pos, const float* __restrict__ mag,
                 const int* __restrict__ nidx, float* __restrict__ out)
{
    const float CUTOFF  = 4.5f;
    const float SPACING = CUTOFF / 7.0f;            // linspace(0,4.5,8) spacing
    const float BETA    = 1.0f / (SPACING * SPACING);
    const float INV_U   = 1.0f / 4.84f;             // 1/max(2.2^2, eps)
    const float PI_F    = 3.14159265358979f;

    const int i = blockIdx.x;
    const int t = threadIdx.x;

    __shared__ float sf[K][R];       // radial basis f[j][r]
    __shared__ float suh[K][3];      // unit vectors vec/d
    __shared__ float smj[K][3];      // neighbor mag
    __shared__ float ss[K];          // s_j = m_i.m_j / U
    __shared__ float suj[K];         // |m_j|^2 / U
    __shared__ float sG[K * R][9];   // G[j*8+b][lc], lc = ch*3 + l

    const float pix = pos[3*i+0], piy = pos[3*i+1], piz = pos[3*i+2];
    const float mix = mag[3*i+0], miy = mag[3*i+1], miz = mag[3*i+2];

    // ---- phase 1: per-neighbor geometry (threads 0..31) ----
    if (t < K) {
        const int n = nidx[i*K + t];
        const float vx = pos[3*n+0] - pix;
        const float vy = pos[3*n+1] - piy;
        const float vz = pos[3*n+2] - piz;
        const float d  = sqrtf(vx*vx + vy*vy + vz*vz + 1e-8f);
        const float rd = 1.0f / d;
        suh[t][0] = vx*rd; suh[t][1] = vy*rd; suh[t][2] = vz*rd;
        const float mjx = mag[3*n+0], mjy = mag[3*n+1], mjz = mag[3*n+2];
        smj[t][0] = mjx; smj[t][1] = mjy; smj[t][2] = mjz;
        ss[t]  = (mix*mjx + miy*mjy + miz*mjz) * INV_U;
        suj[t] = (mjx*mjx + mjy*mjy + mjz*mjz) * INV_U;
        float cut = 0.0f;
        if (d < CUTOFF) cut = 0.5f * (__cosf(PI_F * d / CUTOFF) + 1.0f);
        #pragma unroll
        for (int r = 0; r < R; ++r) {
            const float diff = d - (float)r * SPACING;
            sf[t][r] = __expf(-BETA * diff * diff) * cut;
        }
    }
    __syncthreads();

    // ---- phase 2: G[j][b][lc] = sum_{k>j} c_lc(j,k) * f[k][b] ----
    {
        const int j = t >> 3, b = t & 7;
        float g[9];
        #pragma unroll
        for (int q = 0; q < 9; ++q) g[q] = 0.0f;
        const float ux = suh[j][0], uy = suh[j][1], uz = suh[j][2];
        const float mx = smj[j][0], my = smj[j][1], mz = smj[j][2];
        const float sj = ss[j];
        for (int k = j + 1; k < K; ++k) {
            float c = ux*suh[k][0] + uy*suh[k][1] + uz*suh[k][2];
            c = fminf(1.0f, fmaxf(-1.0f, c));
            const float P1 = c;
            const float P2 = 1.5f*c*c - 0.5f;
            const float w  = (mx*smj[k][0] + my*smj[k][1] + mz*smj[k][2]) * INV_U;
            const float wi = sj * ss[k];
            const float f1 = sf[k][b];
            const float f2 = f1 * w;
            const float f3 = f1 * wi;
            g[0] += f1;      g[1] += P1*f1;  g[2] += P2*f1;   // A_rr channel
            g[3] += f2;      g[4] += P1*f2;  g[5] += P2*f2;   // A_jk channel
            g[6] += f3;      g[7] += P1*f3;  g[8] += P2*f3;   // A_imm channel
        }
        #pragma unroll
        for (int q = 0; q < 9; ++q) sG[t][q] = g[q];
    }
    __syncthreads();

    // ---- phase 3: A[a][b][l] = sum_j f[j][a] * G[j][b][lc]; plus rho sums ----
    if (t < 192) {
        const int ch = t >> 6;          // 0:A_rr 1:A_jk 2:A_imm
        const int ab = t & 63;
        const int a = ab >> 3, b = ab & 7;
        float a0 = 0.0f, a1 = 0.0f, a2 = 0.0f;
        for (int j = 0; j < K; ++j) {
            const float fa = sf[j][a];
            const float* gp = &sG[j*8 + b][ch*3];
            a0 += fa * gp[0];
            a1 += fa * gp[1];
            a2 += fa * gp[2];
        }
        const int chbase = (ch == 0) ? 11 : ((ch == 1) ? 219 : 411);
        const int base = i*DESC + chbase + ab*3;
        out[base+0] = a0; out[base+1] = a1; out[base+2] = a2;
    } else {
        const int u = t - 192;
        if (u < 24) {
            const int which = u >> 3, r = u & 7;
            float sum = 0.0f;
            for (int j = 0; j < K; ++j) {
                const float wj = (which == 0) ? 1.0f : ((which == 1) ? suj[j] : ss[j]);
                sum += wj * sf[j][r];
            }
            const int off = (which == 0) ? 3 : ((which == 1) ? 203 : 211);
            out[i*DESC + off + r] = sum;
        } else if (u == 24) {
            const float un = (mix*mix + miy*miy + miz*miz) * INV_U;
            out[i*DESC + 0] = un;
            out[i*DESC + 1] = un*un;
            out[i*DESC + 2] = un*un*un;
        }
    }
}

extern "C" void kernel_launch(void* const* d_in, const int* in_sizes, int n_in,
                              void* d_out, int out_size, void* d_ws, size_t ws_size,
                              hipStream_t stream) {
    const float* pos  = (const float*)d_in[0];
    const float* mag  = (const float*)d_in[1];
    const int*   nidx = (const int*)d_in[2];
    float* out = (float*)d_out;
    const int n_atoms = in_sizes[2] / K;   // 20000
    desc_kernel<<<n_atoms, 256, 0, stream>>>(pos, mag, nidx, out);
}

// Round 2
// 168.880 us; speedup vs baseline: 1.0078x; 1.0078x over previous
//
#include <hip/hip_runtime.h>

#define K 32
#define R 8
#define DESC 603

__global__ __launch_bounds__(256)
void desc_kernel(const float* __restrict__ pos, const float* __restrict__ mag,
                 const int* __restrict__ nidx, float* __restrict__ out)
{
    const float CUTOFF  = 4.5f;
    const float SPACING = CUTOFF / 7.0f;            // linspace(0,4.5,8) spacing
    const float BETA    = 1.0f / (SPACING * SPACING);
    const float INV_U   = 1.0f / 4.84f;             // 1/max(2.2^2, eps)
    const float INV_MAG = 1.0f / 2.2f;              // sqrt(INV_U)
    const float PI_F    = 3.14159265358979f;

    const int i = blockIdx.x;
    const int t = threadIdx.x;

    __shared__ float  sf[K][R];      // radial basis f[j][r]           (1 KB)
    __shared__ float  suh[K][3];     // unit vectors vec/d
    __shared__ float  smj[K][3];     // neighbor mag, pre-scaled /2.2
    __shared__ float  ss[K];         // s_j = m_i.m_j / U
    __shared__ float  suj[K];        // |m_j|^2 / U
    __shared__ float4 sPair[K][K];   // {P1, P2, w, wi} per (j,k)      (16 KB)
    __shared__ float  sG[K * R][9];  // G[j*8+b][lc], lc = ch*3 + l    (9.2 KB)

    const float pix = pos[3*i+0], piy = pos[3*i+1], piz = pos[3*i+2];
    const float mix = mag[3*i+0], miy = mag[3*i+1], miz = mag[3*i+2];

    // ---- phase 1: per-neighbor geometry (threads 0..31) ----
    if (t < K) {
        const int n = nidx[i*K + t];
        const float vx = pos[3*n+0] - pix;
        const float vy = pos[3*n+1] - piy;
        const float vz = pos[3*n+2] - piz;
        const float d  = sqrtf(vx*vx + vy*vy + vz*vz + 1e-8f);
        const float rd = 1.0f / d;
        suh[t][0] = vx*rd; suh[t][1] = vy*rd; suh[t][2] = vz*rd;
        const float mjx = mag[3*n+0], mjy = mag[3*n+1], mjz = mag[3*n+2];
        smj[t][0] = mjx*INV_MAG; smj[t][1] = mjy*INV_MAG; smj[t][2] = mjz*INV_MAG;
        ss[t]  = (mix*mjx + miy*mjy + miz*mjz) * INV_U;
        suj[t] = (mjx*mjx + mjy*mjy + mjz*mjz) * INV_U;
        float cut = 0.0f;
        if (d < CUTOFF) cut = 0.5f * (__cosf(PI_F * d / CUTOFF) + 1.0f);
        #pragma unroll
        for (int r = 0; r < R; ++r) {
            const float diff = d - (float)r * SPACING;
            sf[t][r] = __expf(-BETA * diff * diff) * cut;
        }
    }
    __syncthreads();

    // ---- phase 2a: pair coefficients, once per (j,k) cell ----
    #pragma unroll
    for (int it = 0; it < 4; ++it) {
        const int cell = it * 256 + t;
        const int j = cell >> 5, k = cell & 31;
        float c = suh[j][0]*suh[k][0] + suh[j][1]*suh[k][1] + suh[j][2]*suh[k][2];
        c = fminf(1.0f, fmaxf(-1.0f, c));
        const float P1 = c;
        const float P2 = 1.5f*c*c - 0.5f;
        const float w  = smj[j][0]*smj[k][0] + smj[j][1]*smj[k][1] + smj[j][2]*smj[k][2];
        const float wi = ss[j] * ss[k];
        sPair[j][k] = make_float4(P1, P2, w, wi);
    }
    __syncthreads();

    // ---- phase 2b: G[j][b][lc] = sum_{k>j} c_lc(j,k) * f[k][b] ----
    {
        const int j = t >> 3, b = t & 7;
        float g[9];
        #pragma unroll
        for (int q = 0; q < 9; ++q) g[q] = 0.0f;
        for (int k = j + 1; k < K; ++k) {
            const float4 p = sPair[j][k];
            const float f1 = sf[k][b];
            const float f2 = f1 * p.z;
            const float f3 = f1 * p.w;
            g[0] += f1;        g[1] += p.x*f1;  g[2] += p.y*f1;   // A_rr
            g[3] += f2;        g[4] += p.x*f2;  g[5] += p.y*f2;   // A_jk
            g[6] += f3;        g[7] += p.x*f3;  g[8] += p.y*f3;   // A_imm
        }
        #pragma unroll
        for (int q = 0; q < 9; ++q) sG[t][q] = g[q];
    }
    __syncthreads();

    // ---- phase 3: A[a][b][l] = sum_j f[j][a] * G[j][b][lc]; plus rho sums ----
    if (t < 192) {
        const int ch = t >> 6;          // 0:A_rr 1:A_jk 2:A_imm
        const int ab = t & 63;
        const int a = ab >> 3, b = ab & 7;
        float a0 = 0.0f, a1 = 0.0f, a2 = 0.0f;
        for (int j = 0; j < K; ++j) {
            const float fa = sf[j][a];
            const float* gp = &sG[j*8 + b][ch*3];
            a0 += fa * gp[0];
            a1 += fa * gp[1];
            a2 += fa * gp[2];
        }
        const int chbase = (ch == 0) ? 11 : ((ch == 1) ? 219 : 411);
        const int base = i*DESC + chbase + ab*3;
        out[base+0] = a0; out[base+1] = a1; out[base+2] = a2;
    } else {
        const int u = t - 192;
        if (u < 24) {
            const int which = u >> 3, r = u & 7;
            float sum = 0.0f;
            for (int j = 0; j < K; ++j) {
                const float wj = (which == 0) ? 1.0f : ((which == 1) ? suj[j] : ss[j]);
                sum += wj * sf[j][r];
            }
            const int off = (which == 0) ? 3 : ((which == 1) ? 203 : 211);
            out[i*DESC + off + r] = sum;
        } else if (u == 24) {
            const float un = (mix*mix + miy*miy + miz*miz) * INV_U;
            out[i*DESC + 0] = un;
            out[i*DESC + 1] = un*un;
            out[i*DESC + 2] = un*un*un;
        }
    }
}

extern "C" void kernel_launch(void* const* d_in, const int* in_sizes, int n_in,
                              void* d_out, int out_size, void* d_ws, size_t ws_size,
                              hipStream_t stream) {
    const float* pos  = (const float*)d_in[0];
    const float* mag  = (const float*)d_in[1];
    const int*   nidx = (const int*)d_in[2];
    float* out = (float*)d_out;
    const int n_atoms = in_sizes[2] / K;   // 20000
    desc_kernel<<<n_atoms, 256, 0, stream>>>(pos, mag, nidx, out);
}

// Round 3
// 100.233 us; speedup vs baseline: 1.6979x; 1.6849x over previous
//
#include <hip/hip_runtime.h>

#define K 32
#define DESC 603

typedef _Float16 h8  __attribute__((ext_vector_type(8)));
typedef _Float16 h4v __attribute__((ext_vector_type(4)));
typedef float    f32x4 __attribute__((ext_vector_type(4)));

// per-wave private LDS region (one atom per wave)
struct __align__(16) WaveLds {
    _Float16 sfT[8][K];     // [b][k] radial basis, f16          512 B
    _Float16 uhx[K], uhy[K], uhz[K];   // unit vectors
    _Float16 mjx[K], mjy[K], mjz[K];   // neighbor mag / 2.2
    _Float16 ssk[K];        // s_k = m_i.m_k / 4.84
    _Float16 suk[K];        // |m_k|^2 / 4.84                    512 B total 8 arrays
    _Float16 GT[80][K];     // [n' = b*9 + q][j], rows 72..79 pad  5120 B
};                           // = 6144 B per wave

__device__ __forceinline__ h8 h8splat(float x) {
    _Float16 h = (_Float16)x;
    h8 r = {h,h,h,h,h,h,h,h};
    return r;
}

__global__ __launch_bounds__(256, 4)
void desc_kernel(const float* __restrict__ pos, const float* __restrict__ mag,
                 const int* __restrict__ nidx, float* __restrict__ out, int natoms)
{
    __shared__ WaveLds lds[4];
    const int w = threadIdx.x >> 6;   // wave id -> atom within block
    const int l = threadIdx.x & 63;   // lane
    int atom = blockIdx.x * 4 + w;
    const bool act = atom < natoms;
    if (!act) atom = natoms - 1;      // clamp; stores predicated on act
    WaveLds& S = lds[w];

    const int col  = l & 15;
    const int quad = l >> 4;
    const int k0   = quad * 8;

    const float CUTOFF  = 4.5f;
    const float SPACING = CUTOFF / 7.0f;
    const float BETA    = 1.0f / (SPACING * SPACING);
    const float INV_U   = 1.0f / 4.84f;
    const float INV_MAG = 1.0f / 2.2f;
    const float PI_F    = 3.14159265358979f;

    const float pix = pos[3*atom+0], piy = pos[3*atom+1], piz = pos[3*atom+2];
    const float mix = mag[3*atom+0], miy = mag[3*atom+1], miz = mag[3*atom+2];

    // ---- phase 1: neighbor geometry -> f16 LDS tables (lanes 0..31) ----
    if (l < K) {
        const int n = nidx[atom*K + l];
        const float vx = pos[3*n+0]-pix, vy = pos[3*n+1]-piy, vz = pos[3*n+2]-piz;
        const float d  = sqrtf(vx*vx + vy*vy + vz*vz + 1e-8f);
        const float rd = 1.0f / d;
        S.uhx[l] = (_Float16)(vx*rd); S.uhy[l] = (_Float16)(vy*rd); S.uhz[l] = (_Float16)(vz*rd);
        const float mjx = mag[3*n+0], mjy = mag[3*n+1], mjz = mag[3*n+2];
        S.mjx[l] = (_Float16)(mjx*INV_MAG);
        S.mjy[l] = (_Float16)(mjy*INV_MAG);
        S.mjz[l] = (_Float16)(mjz*INV_MAG);
        S.ssk[l] = (_Float16)((mix*mjx + miy*mjy + miz*mjz) * INV_U);
        S.suk[l] = (_Float16)((mjx*mjx + mjy*mjy + mjz*mjz) * INV_U);
        float cut = 0.0f;
        if (d < CUTOFF) cut = 0.5f * (__cosf(PI_F * d / CUTOFF) + 1.0f);
        #pragma unroll
        for (int r = 0; r < 8; ++r) {
            const float diff = d - (float)r * SPACING;
            S.sfT[r][l] = (_Float16)(__expf(-BETA * diff * diff) * cut);
        }
    } else {
        // lanes 32..63: zero the GT pad rows (72..79): 32 lanes x 16B = 512B
        const int z = l - 32;
        *(h8*)&S.GT[72 + (z >> 2)][(z & 3) * 8] = h8splat(0.0f);
    }
    if (l == 32 && act) {   // onsite rho_u powers
        const float un = (mix*mix + miy*miy + miz*miz) * INV_U;
        out[atom*DESC+0] = un; out[atom*DESC+1] = un*un; out[atom*DESC+2] = un*un*un;
    }
    __syncthreads();

    // shared fragment: element e = f[k=k0+e][col&7]  (serves as B of phase-2/rho
    // with n=col, and as A of phase-3 with m=a=col)
    const h8 Bf = *(const h8*)&S.sfT[col & 7][k0];

    // ---- rho MFMA: rows {1, u_k, s_k} @ F -> rho_r / rho_uj / rho_s ----
    {
        h8 Ar;
        if      (col == 0) Ar = h8splat(1.0f);
        else if (col == 1) Ar = *(const h8*)&S.suk[k0];
        else if (col == 2) Ar = *(const h8*)&S.ssk[k0];
        else               Ar = h8splat(0.0f);
        f32x4 d = __builtin_amdgcn_mfma_f32_16x16x32_f16(Ar, Bf, (f32x4){0,0,0,0}, 0, 0, 0);
        if (act && quad == 0 && col < 8) {
            out[atom*DESC + 3   + col] = d[0];   // rho_r
            out[atom*DESC + 203 + col] = d[1];   // rho_uj
            out[atom*DESC + 211 + col] = d[2];   // rho_s
        }
    }

    // ---- phase 2: G_q(32x8) = C_q(32x32) @ F(32x8), q = 0..8, two j-tiles ----
    #pragma unroll
    for (int t = 0; t < 2; ++t) {
        const int j = t*16 + col;                    // A-row m = j within tile
        // pair coefficients for (j, k0..k0+7), all packed f16
        const _Float16 jx = S.uhx[j], jy = S.uhy[j], jz = S.uhz[j];
        h8 c = (*(const h8*)&S.uhx[k0]) * jx
             + (*(const h8*)&S.uhy[k0]) * jy
             + (*(const h8*)&S.uhz[k0]) * jz;
        c = __builtin_elementwise_min(h8splat(1.0f),
            __builtin_elementwise_max(h8splat(-1.0f), c));
        const h8 P1 = c;
        const h8 P2 = c * c * h8splat(1.5f) - h8splat(0.5f);
        const _Float16 jmx = S.mjx[j], jmy = S.mjy[j], jmz = S.mjz[j];
        h8 wv = (*(const h8*)&S.mjx[k0]) * jmx
              + (*(const h8*)&S.mjy[k0]) * jmy
              + (*(const h8*)&S.mjz[k0]) * jmz;
        const _Float16 js = S.ssk[j];
        h8 wiv = (*(const h8*)&S.ssk[k0]) * js;
        h8 mk;                                       // mask k > j
        #pragma unroll
        for (int e = 0; e < 8; ++e)
            mk[e] = (_Float16)((k0 + e > j) ? 1.0f : 0.0f);
        const h8 B1 = mk, B2 = wv * mk, B3 = wiv * mk;

        f32x4 acc[9];
        const f32x4 z4 = {0,0,0,0};
        acc[0] = __builtin_amdgcn_mfma_f32_16x16x32_f16(B1,      Bf, z4, 0,0,0);
        acc[1] = __builtin_amdgcn_mfma_f32_16x16x32_f16(B1 * P1, Bf, z4, 0,0,0);
        acc[2] = __builtin_amdgcn_mfma_f32_16x16x32_f16(B1 * P2, Bf, z4, 0,0,0);
        acc[3] = __builtin_amdgcn_mfma_f32_16x16x32_f16(B2,      Bf, z4, 0,0,0);
        acc[4] = __builtin_amdgcn_mfma_f32_16x16x32_f16(B2 * P1, Bf, z4, 0,0,0);
        acc[5] = __builtin_amdgcn_mfma_f32_16x16x32_f16(B2 * P2, Bf, z4, 0,0,0);
        acc[6] = __builtin_amdgcn_mfma_f32_16x16x32_f16(B3,      Bf, z4, 0,0,0);
        acc[7] = __builtin_amdgcn_mfma_f32_16x16x32_f16(B3 * P1, Bf, z4, 0,0,0);
        acc[8] = __builtin_amdgcn_mfma_f32_16x16x32_f16(B3 * P2, Bf, z4, 0,0,0);

        // writeback G^T in f16: D row = j-in-tile = quad*4+reg, col = b
        if (col < 8) {
            #pragma unroll
            for (int q = 0; q < 9; ++q) {
                h4v g;
                g[0] = (_Float16)acc[q][0]; g[1] = (_Float16)acc[q][1];
                g[2] = (_Float16)acc[q][2]; g[3] = (_Float16)acc[q][3];
                *(h4v*)&S.GT[col*9 + q][t*16 + quad*4] = g;
            }
        }
    }
    __syncthreads();

    // ---- phase 3: A_out(8a x 72) = F^T(8x32) @ G(32x72), 5 N-tiles ----
    #pragma unroll
    for (int nt = 0; nt < 5; ++nt) {
        const int n = nt*16 + col;                   // n' = b*9 + ch*3 + l
        const h8 Bg = *(const h8*)&S.GT[n][k0];      // B[k=j][n'] = GT[n'][j]
        const f32x4 d = __builtin_amdgcn_mfma_f32_16x16x32_f16(Bf, Bg, (f32x4){0,0,0,0}, 0,0,0);
        if (act && quad < 2 && n < 72) {
            const int b  = n / 9;
            const int r9 = n - b*9;
            const int ch = r9 / 3;
            const int lg = r9 - ch*3;
            const int base = (ch == 0) ? 11 : ((ch == 1) ? 219 : 411);
            const int a0 = quad * 4;
            #pragma unroll
            for (int reg = 0; reg < 4; ++reg)
                out[atom*DESC + base + ((a0 + reg)*8 + b)*3 + lg] = d[reg];
        }
    }
}

extern "C" void kernel_launch(void* const* d_in, const int* in_sizes, int n_in,
                              void* d_out, int out_size, void* d_ws, size_t ws_size,
                              hipStream_t stream) {
    const float* pos  = (const float*)d_in[0];
    const float* mag  = (const float*)d_in[1];
    const int*   nidx = (const int*)d_in[2];
    float* out = (float*)d_out;
    const int n_atoms = in_sizes[2] / K;            // 20000
    const int blocks = (n_atoms + 3) / 4;
    desc_kernel<<<blocks, 256, 0, stream>>>(pos, mag, nidx, out, n_atoms);
}

// Round 4
// 95.567 us; speedup vs baseline: 1.7808x; 1.0488x over previous
//
#include <hip/hip_runtime.h>

#define K 32
#define DESC 603

typedef _Float16 h8  __attribute__((ext_vector_type(8)));
typedef _Float16 h4v __attribute__((ext_vector_type(4)));
typedef float    f32x4 __attribute__((ext_vector_type(4)));

// Wave-private LDS ordering fence: all lanes of a wave issue LDS ops in
// program order; lgkmcnt(0) guarantees completion. No __syncthreads needed
// since each wave touches only its own WaveLds region.
#define WAVE_LDS_FENCE() __asm__ volatile("s_waitcnt lgkmcnt(0)" ::: "memory")

// per-wave private LDS region (one atom per wave)
struct __align__(16) WaveLds {
    _Float16 sfT[8][K];     // [b][k] radial basis, f16          512 B
    _Float16 uhx[K], uhy[K], uhz[K];   // unit vectors
    _Float16 mjx[K], mjy[K], mjz[K];   // neighbor mag / 2.2
    _Float16 ssk[K];        // s_k = m_i.m_k / 4.84
    _Float16 suk[K];        // |m_k|^2 / 4.84                    512 B total
    _Float16 GT[80][K];     // [n' = ch*24 + b*3 + l][j], rows 72..79 pad  5120 B
};                           // = 6144 B per wave

__device__ __forceinline__ h8 h8splat(float x) {
    _Float16 h = (_Float16)x;
    h8 r = {h,h,h,h,h,h,h,h};
    return r;
}

__global__ __launch_bounds__(256, 4)
void desc_kernel(const float* __restrict__ pos, const float* __restrict__ mag,
                 const int* __restrict__ nidx, float* __restrict__ out, int natoms)
{
    __shared__ WaveLds lds[4];
    const int w = threadIdx.x >> 6;   // wave id -> atom within block
    const int l = threadIdx.x & 63;   // lane
    int atom = blockIdx.x * 4 + w;
    const bool act = atom < natoms;
    if (!act) atom = natoms - 1;      // clamp; stores predicated on act
    WaveLds& S = lds[w];

    const int col  = l & 15;
    const int quad = l >> 4;
    const int k0   = quad * 8;

    const float CUTOFF  = 4.5f;
    const float SPACING = CUTOFF / 7.0f;
    const float BETA    = 1.0f / (SPACING * SPACING);
    const float INV_U   = 1.0f / 4.84f;
    const float INV_MAG = 1.0f / 2.2f;
    const float PI_F    = 3.14159265358979f;

    const float pix = pos[3*atom+0], piy = pos[3*atom+1], piz = pos[3*atom+2];
    const float mix = mag[3*atom+0], miy = mag[3*atom+1], miz = mag[3*atom+2];

    // ---- phase 1: neighbor geometry -> f16 LDS tables (lanes 0..31) ----
    if (l < K) {
        const int n = nidx[atom*K + l];
        const float vx = pos[3*n+0]-pix, vy = pos[3*n+1]-piy, vz = pos[3*n+2]-piz;
        const float d  = sqrtf(vx*vx + vy*vy + vz*vz + 1e-8f);
        const float rd = 1.0f / d;
        S.uhx[l] = (_Float16)(vx*rd); S.uhy[l] = (_Float16)(vy*rd); S.uhz[l] = (_Float16)(vz*rd);
        const float mjx = mag[3*n+0], mjy = mag[3*n+1], mjz = mag[3*n+2];
        S.mjx[l] = (_Float16)(mjx*INV_MAG);
        S.mjy[l] = (_Float16)(mjy*INV_MAG);
        S.mjz[l] = (_Float16)(mjz*INV_MAG);
        S.ssk[l] = (_Float16)((mix*mjx + miy*mjy + miz*mjz) * INV_U);
        S.suk[l] = (_Float16)((mjx*mjx + mjy*mjy + mjz*mjz) * INV_U);
        float cut = 0.0f;
        if (d < CUTOFF) cut = 0.5f * (__cosf(PI_F * d / CUTOFF) + 1.0f);
        #pragma unroll
        for (int r = 0; r < 8; ++r) {
            const float diff = d - (float)r * SPACING;
            S.sfT[r][l] = (_Float16)(__expf(-BETA * diff * diff) * cut);
        }
    } else {
        // lanes 32..63: zero the GT pad rows (72..79): 32 lanes x 16B = 512B
        const int z = l - 32;
        *(h8*)&S.GT[72 + (z >> 2)][(z & 3) * 8] = h8splat(0.0f);
    }
    if (l == 32 && act) {   // onsite rho_u powers
        const float un = (mix*mix + miy*miy + miz*miz) * INV_U;
        out[atom*DESC+0] = un; out[atom*DESC+1] = un*un; out[atom*DESC+2] = un*un*un;
    }
    WAVE_LDS_FENCE();

    // shared fragment: element e = f[k=k0+e][col&7]  (serves as B of phase-2/rho
    // with n=col, and as A of phase-3 with m=a=col)
    const h8 Bf = *(const h8*)&S.sfT[col & 7][k0];

    // ---- rho MFMA: rows {1, u_k, s_k} @ F -> rho_r / rho_uj / rho_s ----
    {
        h8 Ar;
        if      (col == 0) Ar = h8splat(1.0f);
        else if (col == 1) Ar = *(const h8*)&S.suk[k0];
        else if (col == 2) Ar = *(const h8*)&S.ssk[k0];
        else               Ar = h8splat(0.0f);
        f32x4 d = __builtin_amdgcn_mfma_f32_16x16x32_f16(Ar, Bf, (f32x4){0,0,0,0}, 0, 0, 0);
        if (act && quad == 0 && col < 8) {
            out[atom*DESC + 3   + col] = d[0];   // rho_r
            out[atom*DESC + 203 + col] = d[1];   // rho_uj
            out[atom*DESC + 211 + col] = d[2];   // rho_s
        }
    }

    // ---- phase 2: G_q(32x8) = C_q(32x32) @ F(32x8), q = 0..8, two j-tiles ----
    #pragma unroll
    for (int t = 0; t < 2; ++t) {
        const int j = t*16 + col;                    // A-row m = j within tile
        // pair coefficients for (j, k0..k0+7), all packed f16
        const _Float16 jx = S.uhx[j], jy = S.uhy[j], jz = S.uhz[j];
        h8 c = (*(const h8*)&S.uhx[k0]) * jx
             + (*(const h8*)&S.uhy[k0]) * jy
             + (*(const h8*)&S.uhz[k0]) * jz;
        c = __builtin_elementwise_min(h8splat(1.0f),
            __builtin_elementwise_max(h8splat(-1.0f), c));
        const h8 P1 = c;
        const h8 P2 = c * c * h8splat(1.5f) - h8splat(0.5f);
        const _Float16 jmx = S.mjx[j], jmy = S.mjy[j], jmz = S.mjz[j];
        h8 wv = (*(const h8*)&S.mjx[k0]) * jmx
              + (*(const h8*)&S.mjy[k0]) * jmy
              + (*(const h8*)&S.mjz[k0]) * jmz;
        const _Float16 js = S.ssk[j];
        h8 wiv = (*(const h8*)&S.ssk[k0]) * js;
        h8 mk;                                       // mask k > j
        #pragma unroll
        for (int e = 0; e < 8; ++e)
            mk[e] = (_Float16)((k0 + e > j) ? 1.0f : 0.0f);
        const h8 B1 = mk, B2 = wv * mk, B3 = wiv * mk;

        f32x4 acc[9];
        const f32x4 z4 = {0,0,0,0};
        acc[0] = __builtin_amdgcn_mfma_f32_16x16x32_f16(B1,      Bf, z4, 0,0,0);
        acc[1] = __builtin_amdgcn_mfma_f32_16x16x32_f16(B1 * P1, Bf, z4, 0,0,0);
        acc[2] = __builtin_amdgcn_mfma_f32_16x16x32_f16(B1 * P2, Bf, z4, 0,0,0);
        acc[3] = __builtin_amdgcn_mfma_f32_16x16x32_f16(B2,      Bf, z4, 0,0,0);
        acc[4] = __builtin_amdgcn_mfma_f32_16x16x32_f16(B2 * P1, Bf, z4, 0,0,0);
        acc[5] = __builtin_amdgcn_mfma_f32_16x16x32_f16(B2 * P2, Bf, z4, 0,0,0);
        acc[6] = __builtin_amdgcn_mfma_f32_16x16x32_f16(B3,      Bf, z4, 0,0,0);
        acc[7] = __builtin_amdgcn_mfma_f32_16x16x32_f16(B3 * P1, Bf, z4, 0,0,0);
        acc[8] = __builtin_amdgcn_mfma_f32_16x16x32_f16(B3 * P2, Bf, z4, 0,0,0);

        // writeback G^T in f16: D row = j-in-tile = quad*4+reg, b = col
        // GT row n' = ch*24 + b*3 + l  (q = ch*3 + l)
        if (col < 8) {
            const int rowoffs[9] = {0,1,2, 24,25,26, 48,49,50};
            #pragma unroll
            for (int q = 0; q < 9; ++q) {
                h4v g;
                g[0] = (_Float16)acc[q][0]; g[1] = (_Float16)acc[q][1];
                g[2] = (_Float16)acc[q][2]; g[3] = (_Float16)acc[q][3];
                *(h4v*)&S.GT[rowoffs[q] + col*3][t*16 + quad*4] = g;
            }
        }
    }
    WAVE_LDS_FENCE();

    // ---- phase 3: A_out(8a x 72) = F^T(8x32) @ G(32x72), 5 N-tiles ----
    // n' = ch*24 + (b*3 + l): for fixed a, out addr = chbase + a*24 + (n'-ch*24)
    // -> consecutive lanes (n') hit consecutive dwords (coalesced runs of 16).
    #pragma unroll
    for (int nt = 0; nt < 5; ++nt) {
        const int n = nt*16 + col;
        const h8 Bg = *(const h8*)&S.GT[n][k0];      // B[k=j][n'] = GT[n'][j]
        const f32x4 d = __builtin_amdgcn_mfma_f32_16x16x32_f16(Bf, Bg, (f32x4){0,0,0,0}, 0,0,0);
        if (act && quad < 2 && n < 72) {
            const int ch  = n / 24;                  // 0:A_rr 1:A_jk 2:A_imm
            const int off = n - ch*24;               // b*3 + l
            const int cb  = (ch == 0) ? 11 : ((ch == 1) ? 219 : 411);
            const int base = atom*DESC + cb + off + quad*4*24;
            #pragma unroll
            for (int reg = 0; reg < 4; ++reg)
                out[base + reg*24] = d[reg];
        }
    }
}

extern "C" void kernel_launch(void* const* d_in, const int* in_sizes, int n_in,
                              void* d_out, int out_size, void* d_ws, size_t ws_size,
                              hipStream_t stream) {
    const float* pos  = (const float*)d_in[0];
    const float* mag  = (const float*)d_in[1];
    const int*   nidx = (const int*)d_in[2];
    float* out = (float*)d_out;
    const int n_atoms = in_sizes[2] / K;            // 20000
    const int blocks = (n_atoms + 3) / 4;
    desc_kernel<<<blocks, 256, 0, stream>>>(pos, mag, nidx, out, n_atoms);
}

// Round 5
// 91.583 us; speedup vs baseline: 1.8583x; 1.0435x over previous
//
#include <hip/hip_runtime.h>

#define K 32
#define DESC 603

typedef _Float16 h8  __attribute__((ext_vector_type(8)));
typedef _Float16 h4v __attribute__((ext_vector_type(4)));
typedef float    f32x4 __attribute__((ext_vector_type(4)));

// Wave-private LDS; DS ops of one wave execute in order, so lgkmcnt(0)
// suffices for cross-lane RAW within the wave (no __syncthreads needed).
#define WAVE_LDS_FENCE()  __asm__ volatile("s_waitcnt lgkmcnt(0)" ::: "memory")
#define COMPILER_BARRIER() __asm__ volatile("" ::: "memory")

// per-wave LDS layout, in f16 units (total 2816 f16 = 5632 B/wave):
//   [0,256)     sfT[r][k]          radial basis, transposed
//   [256,2816)  GT[80][32]         G^T rows n' = ch*24 + b*3 + l
//   overlay in GT rows 64..71 (dead before first GT writeback):
//     2304+k uhx | 2336+k uhy | 2368+k uhz | 2400+k mjx | 2432+k mjy
//     2464+k mjz | 2496+k ssk | 2528+k suk
//   overlay in GT rows 72..79 (never written by GT writeback; phase-3
//     reads of rows>=72 feed only unstored D columns):
//     2560+k*8  jpack[k] = {uhx,uhy,uhz,0, mjx,mjy,mjz,ss}
#define SFT   0
#define GTB   256
#define UHX   2304
#define UHY   2336
#define UHZ   2368
#define MJX   2400
#define MJY   2432
#define MJZ   2464
#define SSK   2496
#define SUK   2528
#define JPK   2560

__device__ __forceinline__ h8 h8splat(float x) {
    _Float16 h = (_Float16)x;
    h8 r = {h,h,h,h,h,h,h,h};
    return r;
}
__device__ __forceinline__ h8 bc(_Float16 h) {
    h8 r = {h,h,h,h,h,h,h,h};
    return r;
}

__global__ __launch_bounds__(256, 4)
void desc_kernel(const float* __restrict__ pos, const float* __restrict__ mag,
                 const int* __restrict__ nidx, float* __restrict__ out, int natoms)
{
    __shared__ __align__(16) _Float16 ldsbuf[4][2816];
    const int w = threadIdx.x >> 6;
    const int l = threadIdx.x & 63;
    int atom = blockIdx.x * 4 + w;
    const bool act = atom < natoms;
    if (!act) atom = natoms - 1;
    _Float16* W = &ldsbuf[w][0];

    const int col  = l & 15;
    const int quad = l >> 4;
    const int k0   = quad * 8;

    const float CUTOFF  = 4.5f;
    const float SPACING = CUTOFF / 7.0f;
    const float BETA    = 1.0f / (SPACING * SPACING);
    const float INV_U   = 1.0f / 4.84f;
    const float INV_MAG = 1.0f / 2.2f;
    const float PI_F    = 3.14159265358979f;

    const float pix = pos[3*atom+0], piy = pos[3*atom+1], piz = pos[3*atom+2];
    const float mix = mag[3*atom+0], miy = mag[3*atom+1], miz = mag[3*atom+2];

    // ---- phase 1: full-wave gather. lanes 0..31: pos of neighbor k;
    //      lanes 32..63: mag of neighbor k. One unpredicated 3-dword load.
    const int k = l & 31;
    const int n = nidx[atom*K + k];
    const float* src = (l < K) ? (pos + 3*n) : (mag + 3*n);
    const float v0 = src[0], v1 = src[1], v2 = src[2];

    if (l < K) {
        const float vx = v0 - pix, vy = v1 - piy, vz = v2 - piz;
        const float d  = sqrtf(vx*vx + vy*vy + vz*vz + 1e-8f);
        const float rd = 1.0f / d;
        const _Float16 hx = (_Float16)(vx*rd), hy = (_Float16)(vy*rd), hz = (_Float16)(vz*rd);
        W[UHX+k] = hx; W[UHY+k] = hy; W[UHZ+k] = hz;
        h4v jp = {hx, hy, hz, (_Float16)0.0f};
        *(h4v*)&W[JPK + k*8] = jp;
        float cut = 0.0f;
        if (d < CUTOFF) cut = 0.5f * (__cosf(PI_F * d / CUTOFF) + 1.0f);
        #pragma unroll
        for (int r = 0; r < 8; ++r) {
            const float diff = d - (float)r * SPACING;
            W[SFT + r*32 + k] = (_Float16)(__expf(-BETA * diff * diff) * cut);
        }
    } else {
        const float mx = v0*INV_MAG, my = v1*INV_MAG, mz = v2*INV_MAG;
        const float ss = (mix*v0 + miy*v1 + miz*v2) * INV_U;
        const float su = (v0*v0 + v1*v1 + v2*v2) * INV_U;
        const _Float16 hmx = (_Float16)mx, hmy = (_Float16)my, hmz = (_Float16)mz;
        const _Float16 hss = (_Float16)ss, hsu = (_Float16)su;
        W[MJX+k] = hmx; W[MJY+k] = hmy; W[MJZ+k] = hmz;
        W[SSK+k] = hss; W[SUK+k] = hsu;
        h4v jp = {hmx, hmy, hmz, hss};
        *(h4v*)&W[JPK + k*8 + 4] = jp;
    }
    if (l == 32 && act) {
        const float un = (mix*mix + miy*miy + miz*miz) * INV_U;
        out[atom*DESC+0] = un; out[atom*DESC+1] = un*un; out[atom*DESC+2] = un*un*un;
    }
    WAVE_LDS_FENCE();

    // ---- hoisted tile-invariant LDS reads (geom region dies after these) ----
    const h8 Bf   = *(const h8*)&W[SFT + (col&7)*32 + k0];
    const h8 uhx8 = *(const h8*)&W[UHX + k0];
    const h8 uhy8 = *(const h8*)&W[UHY + k0];
    const h8 uhz8 = *(const h8*)&W[UHZ + k0];
    const h8 mjx8 = *(const h8*)&W[MJX + k0];
    const h8 mjy8 = *(const h8*)&W[MJY + k0];
    const h8 mjz8 = *(const h8*)&W[MJZ + k0];
    const h8 ssk8 = *(const h8*)&W[SSK + k0];
    const h8 suk8 = *(const h8*)&W[SUK + k0];
    const h8 jp0  = *(const h8*)&W[JPK + col*8];        // tile0: j = col
    const h8 jp1  = *(const h8*)&W[JPK + (16+col)*8];   // tile1: j = 16+col
    COMPILER_BARRIER();   // GT writebacks below must not hoist above these reads

    // ---- rho MFMA: rows {1, u_k, s_k} @ F ----
    {
        h8 Ar = h8splat(0.0f);
        if      (col == 0) Ar = h8splat(1.0f);
        else if (col == 1) Ar = suk8;
        else if (col == 2) Ar = ssk8;
        f32x4 d = __builtin_amdgcn_mfma_f32_16x16x32_f16(Ar, Bf, (f32x4){0,0,0,0}, 0,0,0);
        if (act && quad == 0 && col < 8) {
            out[atom*DESC + 3   + col] = d[0];   // rho_r
            out[atom*DESC + 203 + col] = d[1];   // rho_uj
            out[atom*DESC + 211 + col] = d[2];   // rho_s
        }
    }

    // ---- phase 2: G_q(32x8) = C_q(32x32) @ F(32x8), two j-tiles ----
    #pragma unroll
    for (int t = 0; t < 2; ++t) {
        const int j  = t*16 + col;
        const h8 jp  = t ? jp1 : jp0;
        h8 c = uhx8*bc(jp[0]) + uhy8*bc(jp[1]) + uhz8*bc(jp[2]);
        c = __builtin_elementwise_min(h8splat(1.0f),
            __builtin_elementwise_max(h8splat(-1.0f), c));
        const h8 P1 = c;
        const h8 P2 = c * c * h8splat(1.5f) - h8splat(0.5f);
        h8 wv  = mjx8*bc(jp[4]) + mjy8*bc(jp[5]) + mjz8*bc(jp[6]);
        h8 wiv = ssk8*bc(jp[7]);
        h8 mk;
        #pragma unroll
        for (int e = 0; e < 8; ++e)
            mk[e] = (_Float16)((k0 + e > j) ? 1.0f : 0.0f);

        const int tcol = t*16 + quad*4;
        const f32x4 z4 = {0,0,0,0};
        // three groups of three MFMAs: keeps only 12 acc VGPRs live
        #pragma unroll
        for (int ch = 0; ch < 3; ++ch) {
            const h8 Bv = (ch == 0) ? mk : (ch == 1) ? wv*mk : wiv*mk;
            f32x4 a0 = __builtin_amdgcn_mfma_f32_16x16x32_f16(Bv,    Bf, z4, 0,0,0);
            f32x4 a1 = __builtin_amdgcn_mfma_f32_16x16x32_f16(Bv*P1, Bf, z4, 0,0,0);
            f32x4 a2 = __builtin_amdgcn_mfma_f32_16x16x32_f16(Bv*P2, Bf, z4, 0,0,0);
            if (col < 8) {
                const int row = ch*24 + col*3;     // n' = ch*24 + b*3 + l
                h4v g0, g1, g2;
                #pragma unroll
                for (int r = 0; r < 4; ++r) {
                    g0[r] = (_Float16)a0[r]; g1[r] = (_Float16)a1[r]; g2[r] = (_Float16)a2[r];
                }
                *(h4v*)&W[GTB + (row+0)*32 + tcol] = g0;
                *(h4v*)&W[GTB + (row+1)*32 + tcol] = g1;
                *(h4v*)&W[GTB + (row+2)*32 + tcol] = g2;
            }
        }
    }
    WAVE_LDS_FENCE();

    // ---- phase 3: A_out(8a x 72) = F^T(8x32) @ G(32x72), 5 N-tiles ----
    // n' >= 72 reads jpack garbage -> lands in D columns that are never stored.
    #pragma unroll
    for (int nt = 0; nt < 5; ++nt) {
        const int n = nt*16 + col;
        const h8 Bg = *(const h8*)&W[GTB + n*32 + k0];
        const f32x4 d = __builtin_amdgcn_mfma_f32_16x16x32_f16(Bf, Bg, (f32x4){0,0,0,0}, 0,0,0);
        if (act && quad < 2 && n < 72) {
            const int ch  = n / 24;
            const int off = n - ch*24;
            const int cb  = (ch == 0) ? 11 : ((ch == 1) ? 219 : 411);
            const int base = atom*DESC + cb + off + quad*96;
            #pragma unroll
            for (int reg = 0; reg < 4; ++reg)
                out[base + reg*24] = d[reg];
        }
    }
}

extern "C" void kernel_launch(void* const* d_in, const int* in_sizes, int n_in,
                              void* d_out, int out_size, void* d_ws, size_t ws_size,
                              hipStream_t stream) {
    const float* pos  = (const float*)d_in[0];
    const float* mag  = (const float*)d_in[1];
    const int*   nidx = (const int*)d_in[2];
    float* out = (float*)d_out;
    const int n_atoms = in_sizes[2] / K;            // 20000
    const int blocks = (n_atoms + 3) / 4;
    desc_kernel<<<blocks, 256, 0, stream>>>(pos, mag, nidx, out, n_atoms);
}

// Round 7
// 90.253 us; speedup vs baseline: 1.8857x; 1.0147x over previous
//
#include <hip/hip_runtime.h>

#define K 32
#define DESC 603

typedef _Float16 h8  __attribute__((ext_vector_type(8)));
typedef _Float16 h4v __attribute__((ext_vector_type(4)));
typedef __fp16   fp16x2 __attribute__((ext_vector_type(2)));
typedef float    f32x4 __attribute__((ext_vector_type(4)));

// Wave-private LDS; DS ops of one wave execute in order, so lgkmcnt(0)
// suffices for cross-lane RAW within the wave (no __syncthreads needed).
#define WAVE_LDS_FENCE()  __asm__ volatile("s_waitcnt lgkmcnt(0)" ::: "memory")
#define COMPILER_BARRIER() __asm__ volatile("" ::: "memory")

// per-wave LDS layout, in f16 units (total 2816 f16 = 5632 B/wave):
//   [0,256)     sfT[r][k]          radial basis, transposed
//   [256,2816)  GT[80][32]         G^T rows n' = ch*24 + b*3 + l
//   overlay in GT rows 64..71 (dead after the hoisted reads; GT writeback
//     touches rows <= 71 only via col<8 -> max row 71):
//     2304+k uhx | 2336+k uhy | 2368+k uhz | 2400+k mjx | 2432+k mjy
//     2464+k mjz | 2496+k ssk | 2528+k suk
//   overlay in GT rows 72..79 (NEVER written by GT writeback, so jp reads
//     may stay inside the tile loop; phase-3 reads of rows>=72 feed only
//     unstored D columns):
//     2560+k*8  jpack[k] = {uhx,uhy,uhz,0, mjx,mjy,mjz,ss}
#define SFT   0
#define GTB   256
#define UHX   2304
#define UHY   2336
#define UHZ   2368
#define MJX   2400
#define MJY   2432
#define MJZ   2464
#define SSK   2496
#define SUK   2528
#define JPK   2560

__device__ __forceinline__ h8 h8splat(float x) {
    _Float16 h = (_Float16)x;
    h8 r = {h,h,h,h,h,h,h,h};
    return r;
}
__device__ __forceinline__ h8 bc(_Float16 h) {
    h8 r = {h,h,h,h,h,h,h,h};
    return r;
}
__device__ __forceinline__ h4v pk4(const f32x4& a) {
    fp16x2 lo = __builtin_amdgcn_cvt_pkrtz(a[0], a[1]);
    fp16x2 hi = __builtin_amdgcn_cvt_pkrtz(a[2], a[3]);
    h4v r;
    r[0] = (_Float16)lo[0]; r[1] = (_Float16)lo[1];
    r[2] = (_Float16)hi[0]; r[3] = (_Float16)hi[1];
    return r;
}

__global__ __launch_bounds__(256, 6)
void desc_kernel(const float* __restrict__ pos, const float* __restrict__ mag,
                 const int* __restrict__ nidx, float* __restrict__ out, int natoms)
{
    __shared__ __align__(16) _Float16 ldsbuf[4][2816];
    const int w = threadIdx.x >> 6;
    const int l = threadIdx.x & 63;
    int atom0 = blockIdx.x * 4 + w;
    const bool act = atom0 < natoms;
    if (!act) atom0 = natoms - 1;
    // wave-uniform atom index: enables SMEM loads for per-atom pos/mag
    const int atom = __builtin_amdgcn_readfirstlane(atom0);
    _Float16* W = &ldsbuf[w][0];

    const int col  = l & 15;
    const int quad = l >> 4;
    const int k0   = quad * 8;

    const float CUTOFF  = 4.5f;
    const float SPACING = CUTOFF / 7.0f;
    const float BETA    = 1.0f / (SPACING * SPACING);
    const float INV_U   = 1.0f / 4.84f;
    const float INV_MAG = 1.0f / 2.2f;
    const float PI_F    = 3.14159265358979f;

    const float pix = pos[3*atom+0], piy = pos[3*atom+1], piz = pos[3*atom+2];
    const float mix = mag[3*atom+0], miy = mag[3*atom+1], miz = mag[3*atom+2];

    // ---- phase 1: full-wave gather. lanes 0..31: pos of neighbor k;
    //      lanes 32..63: mag of neighbor k. One unpredicated 3-dword load.
    const int k = l & 31;
    const int n = nidx[atom*K + k];
    const float* src = (l < K) ? (pos + 3*n) : (mag + 3*n);
    const float v0 = src[0], v1 = src[1], v2 = src[2];

    if (l < K) {
        const float vx = v0 - pix, vy = v1 - piy, vz = v2 - piz;
        const float d  = sqrtf(vx*vx + vy*vy + vz*vz + 1e-8f);
        const float rd = 1.0f / d;
        const _Float16 hx = (_Float16)(vx*rd), hy = (_Float16)(vy*rd), hz = (_Float16)(vz*rd);
        W[UHX+k] = hx; W[UHY+k] = hy; W[UHZ+k] = hz;
        h4v jp = {hx, hy, hz, (_Float16)0.0f};
        *(h4v*)&W[JPK + k*8] = jp;
        float cut = 0.0f;
        if (d < CUTOFF) cut = 0.5f * (__cosf(PI_F * d / CUTOFF) + 1.0f);
        #pragma unroll
        for (int r = 0; r < 8; ++r) {
            const float diff = d - (float)r * SPACING;
            W[SFT + r*32 + k] = (_Float16)(__expf(-BETA * diff * diff) * cut);
        }
    } else {
        const float mx = v0*INV_MAG, my = v1*INV_MAG, mz = v2*INV_MAG;
        const float ss = (mix*v0 + miy*v1 + miz*v2) * INV_U;
        const float su = (v0*v0 + v1*v1 + v2*v2) * INV_U;
        const _Float16 hmx = (_Float16)mx, hmy = (_Float16)my, hmz = (_Float16)mz;
        const _Float16 hss = (_Float16)ss, hsu = (_Float16)su;
        W[MJX+k] = hmx; W[MJY+k] = hmy; W[MJZ+k] = hmz;
        W[SSK+k] = hss; W[SUK+k] = hsu;
        h4v jp = {hmx, hmy, hmz, hss};
        *(h4v*)&W[JPK + k*8 + 4] = jp;
    }
    if (l == 32 && act) {
        const float un = (mix*mix + miy*miy + miz*miz) * INV_U;
        out[atom*DESC+0] = un; out[atom*DESC+1] = un*un; out[atom*DESC+2] = un*un*un;
    }
    WAVE_LDS_FENCE();

    // ---- hoisted tile-invariant LDS reads (geom rows 64..71 die after these) ----
    const h8 Bf   = *(const h8*)&W[SFT + (col&7)*32 + k0];
    const h8 uhx8 = *(const h8*)&W[UHX + k0];
    const h8 uhy8 = *(const h8*)&W[UHY + k0];
    const h8 uhz8 = *(const h8*)&W[UHZ + k0];
    const h8 mjx8 = *(const h8*)&W[MJX + k0];
    const h8 mjy8 = *(const h8*)&W[MJY + k0];
    const h8 mjz8 = *(const h8*)&W[MJZ + k0];
    const h8 ssk8 = *(const h8*)&W[SSK + k0];
    const h8 suk8 = *(const h8*)&W[SUK + k0];
    COMPILER_BARRIER();   // GT writebacks below must not hoist above these reads

    // ---- rho MFMA: rows {1, u_k, s_k} @ F ----
    {
        h8 Ar = h8splat(0.0f);
        if      (col == 0) Ar = h8splat(1.0f);
        else if (col == 1) Ar = suk8;
        else if (col == 2) Ar = ssk8;
        f32x4 d = __builtin_amdgcn_mfma_f32_16x16x32_f16(Ar, Bf, (f32x4){0,0,0,0}, 0,0,0);
        if (act && quad == 0 && col < 8) {
            out[atom*DESC + 3   + col] = d[0];   // rho_r
            out[atom*DESC + 203 + col] = d[1];   // rho_uj
            out[atom*DESC + 211 + col] = d[2];   // rho_s
        }
    }

    // ---- phase 2: G_q(32x8) = C_q(32x32) @ F(32x8), two j-tiles ----
    #pragma unroll
    for (int t = 0; t < 2; ++t) {
        const int j  = t*16 + col;
        const h8 jp  = *(const h8*)&W[JPK + j*8];   // rows 72..79: never clobbered
        h8 c = uhx8*bc(jp[0]) + uhy8*bc(jp[1]) + uhz8*bc(jp[2]);
        c = __builtin_elementwise_min(h8splat(1.0f),
            __builtin_elementwise_max(h8splat(-1.0f), c));
        const h8 P1 = c;
        const h8 P2 = c * c * h8splat(1.5f) - h8splat(0.5f);
        h8 wv  = mjx8*bc(jp[4]) + mjy8*bc(jp[5]) + mjz8*bc(jp[6]);
        h8 wiv = ssk8*bc(jp[7]);
        h8 mk;
        #pragma unroll
        for (int e = 0; e < 8; ++e)
            mk[e] = (_Float16)((k0 + e > j) ? 1.0f : 0.0f);

        const int tcol = t*16 + quad*4;
        const f32x4 z4 = {0,0,0,0};
        // three groups of three MFMAs: keeps only 12 acc VGPRs live
        #pragma unroll
        for (int ch = 0; ch < 3; ++ch) {
            const h8 Bv = (ch == 0) ? mk : (ch == 1) ? wv*mk : wiv*mk;
            f32x4 a0 = __builtin_amdgcn_mfma_f32_16x16x32_f16(Bv,    Bf, z4, 0,0,0);
            f32x4 a1 = __builtin_amdgcn_mfma_f32_16x16x32_f16(Bv*P1, Bf, z4, 0,0,0);
            f32x4 a2 = __builtin_amdgcn_mfma_f32_16x16x32_f16(Bv*P2, Bf, z4, 0,0,0);
            if (col < 8) {
                const int row = ch*24 + col*3;     // n' = ch*24 + b*3 + l
                *(h4v*)&W[GTB + (row+0)*32 + tcol] = pk4(a0);
                *(h4v*)&W[GTB + (row+1)*32 + tcol] = pk4(a1);
                *(h4v*)&W[GTB + (row+2)*32 + tcol] = pk4(a2);
            }
        }
    }
    WAVE_LDS_FENCE();

    // ---- phase 3: A_out(8a x 72) = F^T(8x32) @ G(32x72), 5 N-tiles ----
    // n' >= 72 reads jpack garbage -> lands in D columns that are never stored.
    #pragma unroll
    for (int nt = 0; nt < 5; ++nt) {
        const int n = nt*16 + col;
        const h8 Bg = *(const h8*)&W[GTB + n*32 + k0];
        const f32x4 d = __builtin_amdgcn_mfma_f32_16x16x32_f16(Bf, Bg, (f32x4){0,0,0,0}, 0,0,0);
        if (act && quad < 2 && n < 72) {
            const int ch  = n / 24;
            const int off = n - ch*24;
            const int cb  = (ch == 0) ? 11 : ((ch == 1) ? 219 : 411);
            const int base = atom*DESC + cb + off + quad*96;
            #pragma unroll
            for (int reg = 0; reg < 4; ++reg)
                out[base + reg*24] = d[reg];
        }
    }
}

extern "C" void kernel_launch(void* const* d_in, const int* in_sizes, int n_in,
                              void* d_out, int out_size, void* d_ws, size_t ws_size,
                              hipStream_t stream) {
    const float* pos  = (const float*)d_in[0];
    const float* mag  = (const float*)d_in[1];
    const int*   nidx = (const int*)d_in[2];
    float* out = (float*)d_out;
    const int n_atoms = in_sizes[2] / K;            // 20000
    const int blocks = (n_atoms + 3) / 4;
    desc_kernel<<<blocks, 256, 0, stream>>>(pos, mag, nidx, out, n_atoms);
}